// Round 3
// baseline (244.334 us; speedup 1.0000x reference)
//
#include <hip/hip_runtime.h>
#include <hip/hip_bf16.h>

// B=256, C_IN=6, L=512, C1=32, C2=D=64, NCLASS=10.
// ws layout (bytes): qo bf16 @0, ko bf16 @16.7M, vt bf16 [b][d][key] @33.5M,
//                    partial fp32 @50.3M.

#define NB 256
#define LL 512
#define CIN 6
#define C1 32
#define C2 64
#define NCLASS 10

typedef __bf16 bf16x8 __attribute__((ext_vector_type(8)));
typedef float f32x4 __attribute__((ext_vector_type(4)));

static __device__ __forceinline__ unsigned short f2b(float f) {
    __bf16 h = (__bf16)f;                       // RNE f32->bf16
    return __builtin_bit_cast(unsigned short, h);
}

// ---------------------------------------------------------------------------
// Kernel A (fused): conv1(VALU) -> conv2(MFMA GEMM, im2col-free via k'=dl*32+ci
// packing) -> bn2+relu -> qkv MFMA projections. Block = (b, half of L) = 256 rows.
// h never goes to HBM. LDS union keeps total at 67.8 KB -> 2 blocks/CU.
// ---------------------------------------------------------------------------
__global__ __launch_bounds__(256) void conv_qkv(
    const float* __restrict__ x,
    const float* __restrict__ w1, const float* __restrict__ cb1,
    const float* __restrict__ g1, const float* __restrict__ be1,
    const float* __restrict__ m1, const float* __restrict__ v1,
    const float* __restrict__ w2, const float* __restrict__ cb2,
    const float* __restrict__ g2, const float* __restrict__ be2,
    const float* __restrict__ m2, const float* __restrict__ v2,
    const float* __restrict__ wq, const float* __restrict__ bq,
    const float* __restrict__ wk, const float* __restrict__ bk,
    const float* __restrict__ wv, const float* __restrict__ bv,
    unsigned short* __restrict__ qo, unsigned short* __restrict__ ko,
    unsigned short* __restrict__ vt)
{
    const int b  = blockIdx.x;
    const int l0 = blockIdx.y * 256;
    const int t  = threadIdx.x;
    const int w = t >> 6, lane = t & 63, quad = lane >> 4, lc = lane & 15;
    const int rowbase = b * LL + l0;

    // LDS union region U (40192 B) + persistent Ws (27648 B) = 67840 B.
    // U timeline: {xs,h1b,W2s} -> Hs -> Vs  (barriers at each hand-off)
    __shared__ __align__(16) char smem[67840];
    float*          xs  = (float*)smem;                       // [6][260] f32
    unsigned short* h1b = (unsigned short*)(smem + 6240);     // [258][40] bf16
    unsigned short* W2s = (unsigned short*)(smem + 26880);    // [64][104] bf16
    unsigned short* Hs  = (unsigned short*)smem;              // [256][72] bf16
    unsigned short* Vs  = (unsigned short*)smem;              // [64][264] bf16
    unsigned short* Ws  = (unsigned short*)(smem + 40192);    // [3][64][72] bf16

    // ---- P0: stage weights + x slice -------------------------------------
    for (int idx = t; idx < 4096; idx += 256) {
        int r = idx >> 6, c = idx & 63;
        Ws[(0 * 64 + r) * 72 + c] = f2b(wq[idx]);
        Ws[(1 * 64 + r) * 72 + c] = f2b(wk[idx]);
        Ws[(2 * 64 + r) * 72 + c] = f2b(wv[idx]);
    }
    for (int idx = t; idx < 6144; idx += 256) {
        int c2 = idx / 96, r = idx % 96, ci = r / 3, dl = r % 3;
        W2s[c2 * 104 + dl * 32 + ci] = f2b(w2[idx]);   // W2s[c2][k'=dl*32+ci]
    }
    for (int idx = t; idx < CIN * 260; idx += 256) {
        int c = idx / 260, j = idx % 260;
        int l = l0 - 2 + j;
        xs[c * 260 + j] = (l >= 0 && l < LL) ? x[((size_t)b * CIN + c) * LL + l] : 0.f;
    }
    __syncthreads();

    // ---- P2: conv1 + bn1 + relu -> h1b[j][ci] bf16 (pos p = l0-1+j) ------
    for (int idx = t; idx < 258 * C1; idx += 256) {
        int j = idx >> 5, c = idx & 31;
        int p = l0 - 1 + j;
        float y = 0.f;
        if (p >= 0 && p < LL) {
            float inv = g1[c] * rsqrtf(v1[c] + 1e-5f);
            float sh  = be1[c] + (cb1[c] - m1[c]) * inv;
            float acc = 0.f;
            #pragma unroll
            for (int ci = 0; ci < CIN; ci++) {
                const float* wp = w1 + (c * CIN + ci) * 3;
                acc += xs[ci * 260 + j] * wp[0] + xs[ci * 260 + j + 1] * wp[1]
                     + xs[ci * 260 + j + 2] * wp[2];
            }
            y = acc * inv + sh;
            y = y > 0.f ? y : 0.f;
        }
        h1b[j * 40 + c] = f2b(y);
    }
    __syncthreads();

    // ---- P4: conv2 as GEMM M=256,N=64,K=96 (k'=dl*32+ci) -----------------
    // A[r][k'] = h1b[r+dl][ci] -> contiguous b128 frag at &h1b[row+kc][quad*8]
    bf16x8 aC[4][3], bC[4][3];
    #pragma unroll
    for (int mt = 0; mt < 4; mt++)
        #pragma unroll
        for (int kc = 0; kc < 3; kc++)
            aC[mt][kc] = *(const bf16x8*)&h1b[(w * 64 + mt * 16 + lc + kc) * 40 + quad * 8];
    #pragma unroll
    for (int nt = 0; nt < 4; nt++)
        #pragma unroll
        for (int kc = 0; kc < 3; kc++)
            bC[nt][kc] = *(const bf16x8*)&W2s[(nt * 16 + lc) * 104 + kc * 32 + quad * 8];

    f32x4 acc2[4][4];
    #pragma unroll
    for (int mt = 0; mt < 4; mt++)
        #pragma unroll
        for (int nt = 0; nt < 4; nt++) {
            f32x4 a = {0.f, 0.f, 0.f, 0.f};
            a = __builtin_amdgcn_mfma_f32_16x16x32_bf16(aC[mt][0], bC[nt][0], a, 0, 0, 0);
            a = __builtin_amdgcn_mfma_f32_16x16x32_bf16(aC[mt][1], bC[nt][1], a, 0, 0, 0);
            acc2[mt][nt] = __builtin_amdgcn_mfma_f32_16x16x32_bf16(aC[mt][2], bC[nt][2], a, 0, 0, 0);
        }
    __syncthreads();                     // h1b/W2s dead -> U becomes Hs

    // ---- P6: bn2 + relu, C-layout -> Hs[row][c2] -------------------------
    #pragma unroll
    for (int nt = 0; nt < 4; nt++) {
        int c2 = nt * 16 + lc;
        float inv2 = g2[c2] * rsqrtf(v2[c2] + 1e-5f);
        float sh2  = be2[c2] + (cb2[c2] - m2[c2]) * inv2;
        #pragma unroll
        for (int mt = 0; mt < 4; mt++)
            #pragma unroll
            for (int reg = 0; reg < 4; reg++) {
                float y = acc2[mt][nt][reg] * inv2 + sh2;
                y = y > 0.f ? y : 0.f;
                int row = w * 64 + mt * 16 + quad * 4 + reg;
                Hs[row * 72 + c2] = f2b(y);
            }
    }
    __syncthreads();

    // ---- P8: h A-frags from Hs -------------------------------------------
    bf16x8 aH[4][2];
    #pragma unroll
    for (int mt = 0; mt < 4; mt++)
        #pragma unroll
        for (int kc = 0; kc < 2; kc++)
            aH[mt][kc] = *(const bf16x8*)&Hs[(w * 64 + mt * 16 + lc) * 72 + kc * 32 + quad * 8];
    __syncthreads();                     // Hs dead -> U becomes Vs

    // ---- P10: q/k/v projections ------------------------------------------
    const float* bias[3] = {bq, bk, bv};
    for (int p = 0; p < 3; p++) {
        bf16x8 bW[4][2];
        float bb[4];
        #pragma unroll
        for (int nt = 0; nt < 4; nt++) {
            #pragma unroll
            for (int kc = 0; kc < 2; kc++)
                bW[nt][kc] = *(const bf16x8*)&Ws[(p * 64 + nt * 16 + lc) * 72 + quad * 8 + kc * 32];
            bb[nt] = bias[p][nt * 16 + lc];
        }
        #pragma unroll
        for (int mt = 0; mt < 4; mt++) {
            f32x4 acc[4];
            #pragma unroll
            for (int nt = 0; nt < 4; nt++) {
                f32x4 a = {0.f, 0.f, 0.f, 0.f};
                a = __builtin_amdgcn_mfma_f32_16x16x32_bf16(aH[mt][0], bW[nt][0], a, 0, 0, 0);
                acc[nt] = __builtin_amdgcn_mfma_f32_16x16x32_bf16(aH[mt][1], bW[nt][1], a, 0, 0, 0);
            }
            const int rloc = w * 64 + mt * 16 + quad * 4;   // + reg
            #pragma unroll
            for (int nt = 0; nt < 4; nt++) {
                const int dout = nt * 16 + lc;
                #pragma unroll
                for (int reg = 0; reg < 4; reg++) {
                    float val = acc[nt][reg] + bb[nt];
                    unsigned short bits = f2b(val);
                    if (p == 0)      qo[(size_t)(rowbase + rloc + reg) * 64 + dout] = bits;
                    else if (p == 1) ko[(size_t)(rowbase + rloc + reg) * 64 + dout] = bits;
                    else             Vs[dout * 264 + rloc + reg] = bits;
                }
            }
        }
    }
    __syncthreads();
    // coalesced vt[b][d][l0 .. l0+255] writes (16B per lane)
    #pragma unroll
    for (int i = 0; i < 8; i++) {
        int flat = t * 8 + i * 2048;     // 64*256 elems
        int d = flat >> 8, kl = flat & 255;
        uint4 vv = *(const uint4*)&Vs[d * 264 + kl];
        *(uint4*)(vt + (((size_t)b * 64 + d) << 9) + l0 + kl) = vv;
    }
}

// ---------------------------------------------------------------------------
// Kernel B: MFMA flash attention (no-max softmax; |scores|*scale ~ 1e-3) +
// pooling. Block = (b, q-tile of 64 rows). K and V fragments read DIRECT from
// global (single HBM pass; L1/L2 + b%8 XCD swizzle give reuse) -> LDS ~6 KB,
// 5 blocks/CU via __launch_bounds__(256,5).
// ---------------------------------------------------------------------------
__global__ __launch_bounds__(256, 5) void attn_mfma(
    const unsigned short* __restrict__ q, const unsigned short* __restrict__ k,
    const unsigned short* __restrict__ vt, float* __restrict__ partial)
{
    const int b = blockIdx.x, qt = blockIdx.y, t = threadIdx.x;
    const int w = t >> 6, lane = t & 63, quad = lane >> 4, lc = lane & 15;

    __shared__ unsigned short Ps[4][16][40];   // per-wave P C->A transform
    __shared__ float red[4][64];

    // Q A-frags (direct from global, 16B/lane)
    bf16x8 aQ[2];
    {
        const unsigned short* qrow = q + ((size_t)(b * LL + qt * 64 + w * 16 + lc) << 6);
        aQ[0] = *(const bf16x8*)(qrow + quad * 8);
        aQ[1] = *(const bf16x8*)(qrow + quad * 8 + 32);
    }

    f32x4 outacc[4];
    #pragma unroll
    for (int dt = 0; dt < 4; dt++) outacc[dt] = (f32x4){0.f, 0.f, 0.f, 0.f};
    float den[4] = {0.f, 0.f, 0.f, 0.f};

    const unsigned short* kb = k + ((size_t)b * LL << 6);
    const unsigned short* vb = vt + ((size_t)b << 15);

    for (int c = 0; c < 16; c++) {             // 16 chunks of 32 keys
        #pragma unroll
        for (int nt = 0; nt < 2; nt++) {
            const unsigned short* krow = kb + (size_t)(c * 32 + nt * 16 + lc) * 64 + quad * 8;
            bf16x8 bK0 = *(const bf16x8*)(krow);
            bf16x8 bK1 = *(const bf16x8*)(krow + 32);
            f32x4 s = {0.f, 0.f, 0.f, 0.f};
            s = __builtin_amdgcn_mfma_f32_16x16x32_bf16(aQ[0], bK0, s, 0, 0, 0);
            s = __builtin_amdgcn_mfma_f32_16x16x32_bf16(aQ[1], bK1, s, 0, 0, 0);
            #pragma unroll
            for (int reg = 0; reg < 4; reg++) {
                float p = __expf(s[reg] * 0.125f);   // 1/sqrt(64)
                den[reg] += p;
                Ps[w][quad * 4 + reg][lc + nt * 16] = f2b(p);
            }
        }
        // P: C-layout -> A-layout via per-wave LDS (in-order DS pipe, no barrier)
        bf16x8 aP = *(const bf16x8*)&Ps[w][lc][quad * 8];
        #pragma unroll
        for (int dt = 0; dt < 4; dt++) {
            bf16x8 bV = *(const bf16x8*)(vb + (size_t)(dt * 16 + lc) * 512 + c * 32 + quad * 8);
            outacc[dt] = __builtin_amdgcn_mfma_f32_16x16x32_bf16(aP, bV, outacc[dt], 0, 0, 0);
        }
    }

    // denominator: reduce across the quad's 16 lanes (keys)
    #pragma unroll
    for (int reg = 0; reg < 4; reg++) {
        float d2 = den[reg];
        d2 += __shfl_xor(d2, 1);  d2 += __shfl_xor(d2, 2);
        d2 += __shfl_xor(d2, 4);  d2 += __shfl_xor(d2, 8);
        den[reg] = d2;
    }
    // pooled partial: sum_i out[i][d]/den[i] over this wave's 16 rows
    #pragma unroll
    for (int dt = 0; dt < 4; dt++) {
        float ps = 0.f;
        #pragma unroll
        for (int reg = 0; reg < 4; reg++) ps += outacc[dt][reg] / den[reg];
        ps += __shfl_xor(ps, 16);
        ps += __shfl_xor(ps, 32);
        if (quad == 0) red[w][dt * 16 + lc] = ps;
    }
    __syncthreads();
    if (t < 64)
        partial[((size_t)(b * 8 + qt) << 6) + t] =
            red[0][t] + red[1][t] + red[2][t] + red[3][t];
}

// ---------------------------------------------------------------------------
// Kernel C: pooled = (sum of 8 partials)/512 ; logits = pooled @ fc_w^T + fc_b
// ---------------------------------------------------------------------------
__global__ __launch_bounds__(64) void fc_kernel(
    const float* __restrict__ partial,
    const float* __restrict__ fcw, const float* __restrict__ fcb,
    float* __restrict__ outp)
{
    const int b = blockIdx.x, t = threadIdx.x;
    __shared__ float pool[64];
    float s = 0.f;
    #pragma unroll
    for (int p = 0; p < 8; p++) s += partial[((size_t)b * 8 + p) * 64 + t];
    pool[t] = s * (1.0f / 512.0f);
    __syncthreads();
    if (t < NCLASS) {
        float acc = fcb[t];
        #pragma unroll
        for (int d = 0; d < 64; d++) acc += pool[d] * fcw[t * 64 + d];
        outp[b * NCLASS + t] = acc;
    }
}

// ---------------------------------------------------------------------------
extern "C" void kernel_launch(void* const* d_in, const int* in_sizes, int n_in,
                              void* d_out, int out_size, void* d_ws, size_t ws_size,
                              hipStream_t stream)
{
    const float* x   = (const float*)d_in[0];
    const float* w1  = (const float*)d_in[1];
    const float* cb1 = (const float*)d_in[2];
    const float* g1  = (const float*)d_in[3];
    const float* be1 = (const float*)d_in[4];
    const float* m1  = (const float*)d_in[5];
    const float* v1  = (const float*)d_in[6];
    const float* w2  = (const float*)d_in[7];
    const float* cb2 = (const float*)d_in[8];
    const float* g2  = (const float*)d_in[9];
    const float* be2 = (const float*)d_in[10];
    const float* m2  = (const float*)d_in[11];
    const float* v2  = (const float*)d_in[12];
    const float* wq  = (const float*)d_in[13];
    const float* bq  = (const float*)d_in[14];
    const float* wk  = (const float*)d_in[15];
    const float* bk  = (const float*)d_in[16];
    const float* wv  = (const float*)d_in[17];
    const float* bv  = (const float*)d_in[18];
    const float* fcw = (const float*)d_in[19];
    const float* fcb = (const float*)d_in[20];
    float* out = (float*)d_out;

    char* ws = (char*)d_ws;
    unsigned short* qo = (unsigned short*)(ws);                 // 16,777,216 B
    unsigned short* ko = (unsigned short*)(ws + 16777216u);
    unsigned short* vt = (unsigned short*)(ws + 33554432u);
    float* partial     = (float*)(ws + 50331648u);

    conv_qkv<<<dim3(NB, 2), 256, 0, stream>>>(x, w1, cb1, g1, be1, m1, v1,
                                              w2, cb2, g2, be2, m2, v2,
                                              wq, bq, wk, bk, wv, bv,
                                              qo, ko, vt);
    attn_mfma<<<dim3(NB, 8), 256, 0, stream>>>(qo, ko, vt, partial);
    fc_kernel<<<dim3(NB), 64, 0, stream>>>(partial, fcw, fcb, out);
}

// Round 5
// 177.719 us; speedup vs baseline: 1.3748x; 1.3748x over previous
//
#include <hip/hip_runtime.h>
#include <hip/hip_bf16.h>

// B=256, C_IN=6, L=512, C1=32, C2=D=64, NCLASS=10.
// ws: qo bf16 @0, ko bf16 @16M, vt bf16 [b][d][key] @32M, partial f32 @48M.

#define NB 256
#define LL 512
#define CIN 6
#define C1 32
#define C2 64
#define NCLASS 10

typedef __bf16 bf16x8 __attribute__((ext_vector_type(8)));
typedef float f32x4 __attribute__((ext_vector_type(4)));
typedef unsigned short us4 __attribute__((ext_vector_type(4)));

static __device__ __forceinline__ unsigned short f2b(float f) {
    __bf16 h = (__bf16)f;                       // RNE f32->bf16
    return __builtin_bit_cast(unsigned short, h);
}

// ---------------------------------------------------------------------------
// Kernel A (fused): conv1(VALU) -> conv2(MFMA, C'=W2·X^T) -> bn2+relu ->
// q/k (C'=W·H^T, regs along d -> short4 LDS pack -> coalesced stores) ->
// v (H·Wv^T, regs along keys -> short4 pack -> coalesced [d][key] stores).
// Block = (b, 128 L-rows). Peak LDS 26.9 KB. No scattered global stores.
// ---------------------------------------------------------------------------
__global__ __launch_bounds__(256) void conv_qkv(
    const float* __restrict__ x,
    const float* __restrict__ w1, const float* __restrict__ cb1,
    const float* __restrict__ g1, const float* __restrict__ be1,
    const float* __restrict__ m1, const float* __restrict__ v1,
    const float* __restrict__ w2, const float* __restrict__ cb2,
    const float* __restrict__ g2, const float* __restrict__ be2,
    const float* __restrict__ m2, const float* __restrict__ v2,
    const float* __restrict__ wq, const float* __restrict__ bq,
    const float* __restrict__ wk, const float* __restrict__ bk,
    const float* __restrict__ wv, const float* __restrict__ bvp,
    unsigned short* __restrict__ qo, unsigned short* __restrict__ ko,
    unsigned short* __restrict__ vt)
{
    const int b  = blockIdx.x;
    const int l0 = blockIdx.y * 128;
    const int t  = threadIdx.x;
    const int w = t >> 6, lane = t & 63, quad = lane >> 4, lc = lane & 15;
    const int rowbase = b * LL + l0;

    // region layout (aliased phases):
    //   A: xs[6][132] f32 @0 | h1b[130][40] @3168 | W2s[64][104] @13568  (26880 B)
    //   B: Hs[128][72] @0 (18432 B)   C: Cs[128][72] @0   D: Vs[64][136] @0
    __shared__ __align__(16) char smem[26880];
    float*          xs  = (float*)smem;
    unsigned short* h1b = (unsigned short*)(smem + 3168);
    unsigned short* W2s = (unsigned short*)(smem + 13568);
    unsigned short* Hs  = (unsigned short*)smem;
    unsigned short* Cs  = (unsigned short*)smem;
    unsigned short* Vs  = (unsigned short*)smem;

    // ---- stage W2 (packed k' = dl*32+ci) + x slice -----------------------
    for (int idx = t; idx < 6144; idx += 256) {
        int c2 = idx / 96, r = idx % 96, ci = r / 3, dl = r % 3;
        W2s[c2 * 104 + dl * 32 + ci] = f2b(w2[idx]);
    }
    for (int idx = t; idx < CIN * 132; idx += 256) {
        int c = idx / 132, j = idx % 132;
        int l = l0 - 2 + j;
        xs[c * 132 + j] = (l >= 0 && l < LL) ? x[((size_t)b * CIN + c) * LL + l] : 0.f;
    }
    __syncthreads();

    // ---- conv1 + bn1 + relu -> h1b[j][ci], j=0..129 <-> pos l0-1+j -------
    for (int idx = t; idx < 130 * C1; idx += 256) {
        int j = idx >> 5, c = idx & 31;
        int p = l0 - 1 + j;
        float y = 0.f;
        if (p >= 0 && p < LL) {
            float inv = g1[c] * rsqrtf(v1[c] + 1e-5f);
            float sh  = be1[c] + (cb1[c] - m1[c]) * inv;
            float acc = 0.f;
            #pragma unroll
            for (int ci = 0; ci < CIN; ci++) {
                const float* wp = w1 + (c * CIN + ci) * 3;
                acc += xs[ci * 132 + j] * wp[0] + xs[ci * 132 + j + 1] * wp[1]
                     + xs[ci * 132 + j + 2] * wp[2];
            }
            y = acc * inv + sh;
            y = y > 0.f ? y : 0.f;
        }
        h1b[j * 40 + c] = f2b(y);
    }
    __syncthreads();

    // ---- conv2: C' = W2 · X^T  (M=64 c2, N=128 rows, K=96) ---------------
    bf16x8 bX[2][3], aW2[4][3];
    #pragma unroll
    for (int mt = 0; mt < 2; mt++)
        #pragma unroll
        for (int kc = 0; kc < 3; kc++)
            bX[mt][kc] = *(const bf16x8*)&h1b[(w * 32 + mt * 16 + lc + kc) * 40 + quad * 8];
    #pragma unroll
    for (int nt = 0; nt < 4; nt++)
        #pragma unroll
        for (int kc = 0; kc < 3; kc++)
            aW2[nt][kc] = *(const bf16x8*)&W2s[(nt * 16 + lc) * 104 + kc * 32 + quad * 8];

    f32x4 acc2[4][2];                      // [c2-tile nt][row-tile mt]
    #pragma unroll
    for (int nt = 0; nt < 4; nt++)
        #pragma unroll
        for (int mt = 0; mt < 2; mt++) {
            f32x4 a = {0.f, 0.f, 0.f, 0.f};
            a = __builtin_amdgcn_mfma_f32_16x16x32_bf16(aW2[nt][0], bX[mt][0], a, 0, 0, 0);
            a = __builtin_amdgcn_mfma_f32_16x16x32_bf16(aW2[nt][1], bX[mt][1], a, 0, 0, 0);
            acc2[nt][mt] = __builtin_amdgcn_mfma_f32_16x16x32_bf16(aW2[nt][2], bX[mt][2], a, 0, 0, 0);
        }
    __syncthreads();                       // region A dead

    // ---- bn2 + relu -> Hs[row][c2] (short4: regs are consecutive c2) -----
    #pragma unroll
    for (int nt = 0; nt < 4; nt++) {
        const float4 gv  = *(const float4*)&g2[nt * 16 + quad * 4];
        const float4 vv  = *(const float4*)&v2[nt * 16 + quad * 4];
        const float4 bev = *(const float4*)&be2[nt * 16 + quad * 4];
        const float4 cbv = *(const float4*)&cb2[nt * 16 + quad * 4];
        const float4 mv  = *(const float4*)&m2[nt * 16 + quad * 4];
        float inv[4], sh[4];
        inv[0] = gv.x * rsqrtf(vv.x + 1e-5f); sh[0] = bev.x + (cbv.x - mv.x) * inv[0];
        inv[1] = gv.y * rsqrtf(vv.y + 1e-5f); sh[1] = bev.y + (cbv.y - mv.y) * inv[1];
        inv[2] = gv.z * rsqrtf(vv.z + 1e-5f); sh[2] = bev.z + (cbv.z - mv.z) * inv[2];
        inv[3] = gv.w * rsqrtf(vv.w + 1e-5f); sh[3] = bev.w + (cbv.w - mv.w) * inv[3];
        #pragma unroll
        for (int mt = 0; mt < 2; mt++) {
            us4 pk;
            #pragma unroll
            for (int r = 0; r < 4; r++) {
                float y = acc2[nt][mt][r] * inv[r] + sh[r];
                y = y > 0.f ? y : 0.f;
                pk[r] = f2b(y);
            }
            *(us4*)&Hs[(w * 32 + mt * 16 + lc) * 72 + nt * 16 + quad * 4] = pk;
        }
    }
    __syncthreads();

    // ---- H frags (serve as both A and B operands: lane=row, k=d) ---------
    bf16x8 aH[2][2];
    #pragma unroll
    for (int mt = 0; mt < 2; mt++)
        #pragma unroll
        for (int kc = 0; kc < 2; kc++)
            aH[mt][kc] = *(const bf16x8*)&Hs[(w * 32 + mt * 16 + lc) * 72 + kc * 32 + quad * 8];
    __syncthreads();                       // Hs dead -> Cs

    // ---- q, k: C' = W · H^T; regs along dout -> short4 pack --------------
    for (int p = 0; p < 2; p++) {
        const float* wsrc = p ? wk : wq;
        const float* bsrc = p ? bk : bq;
        unsigned short* osrc = p ? ko : qo;
        #pragma unroll
        for (int nt = 0; nt < 4; nt++) {
            bf16x8 aW[2];
            #pragma unroll
            for (int kc = 0; kc < 2; kc++) {
                const float* wp = wsrc + (size_t)(nt * 16 + lc) * 64 + kc * 32 + quad * 8;
                float4 f0 = *(const float4*)wp;
                float4 f1 = *(const float4*)(wp + 4);
                bf16x8 tmp;
                tmp[0] = (__bf16)f0.x; tmp[1] = (__bf16)f0.y;
                tmp[2] = (__bf16)f0.z; tmp[3] = (__bf16)f0.w;
                tmp[4] = (__bf16)f1.x; tmp[5] = (__bf16)f1.y;
                tmp[6] = (__bf16)f1.z; tmp[7] = (__bf16)f1.w;
                aW[kc] = tmp;
            }
            const float4 bb = *(const float4*)&bsrc[nt * 16 + quad * 4];
            #pragma unroll
            for (int mt = 0; mt < 2; mt++) {
                f32x4 a = {0.f, 0.f, 0.f, 0.f};
                a = __builtin_amdgcn_mfma_f32_16x16x32_bf16(aW[0], aH[mt][0], a, 0, 0, 0);
                a = __builtin_amdgcn_mfma_f32_16x16x32_bf16(aW[1], aH[mt][1], a, 0, 0, 0);
                us4 pk;
                pk[0] = f2b(a[0] + bb.x); pk[1] = f2b(a[1] + bb.y);
                pk[2] = f2b(a[2] + bb.z); pk[3] = f2b(a[3] + bb.w);
                *(us4*)&Cs[(w * 32 + mt * 16 + lc) * 72 + nt * 16 + quad * 4] = pk;
            }
        }
        __syncthreads();
        // 128x64 shorts = 1024 uint4 -> 4 iterations of 256 threads
        #pragma unroll
        for (int i = 0; i < 4; i++) {
            int idx = i * 256 + t;             // [0,1024)
            int row = idx >> 3, dcol = (idx & 7) * 8;
            uint4 rd = *(const uint4*)&Cs[row * 72 + dcol];
            *(uint4*)(osrc + (size_t)(rowbase + row) * 64 + dcol) = rd;
        }
        __syncthreads();
    }

    // ---- v: H · Wv^T; regs along rows -> short4 pack into Vs[d][row] -----
    #pragma unroll
    for (int nt = 0; nt < 4; nt++) {
        bf16x8 bW[2];
        #pragma unroll
        for (int kc = 0; kc < 2; kc++) {
            const float* wp = wv + (size_t)(nt * 16 + lc) * 64 + kc * 32 + quad * 8;
            float4 f0 = *(const float4*)wp;
            float4 f1 = *(const float4*)(wp + 4);
            bf16x8 tmp;
            tmp[0] = (__bf16)f0.x; tmp[1] = (__bf16)f0.y;
            tmp[2] = (__bf16)f0.z; tmp[3] = (__bf16)f0.w;
            tmp[4] = (__bf16)f1.x; tmp[5] = (__bf16)f1.y;
            tmp[6] = (__bf16)f1.z; tmp[7] = (__bf16)f1.w;
            bW[kc] = tmp;
        }
        const float bvv = bvp[nt * 16 + lc];
        #pragma unroll
        for (int mt = 0; mt < 2; mt++) {
            f32x4 a = {0.f, 0.f, 0.f, 0.f};
            a = __builtin_amdgcn_mfma_f32_16x16x32_bf16(aH[mt][0], bW[0], a, 0, 0, 0);
            a = __builtin_amdgcn_mfma_f32_16x16x32_bf16(aH[mt][1], bW[1], a, 0, 0, 0);
            us4 pk;
            pk[0] = f2b(a[0] + bvv); pk[1] = f2b(a[1] + bvv);
            pk[2] = f2b(a[2] + bvv); pk[3] = f2b(a[3] + bvv);
            *(us4*)&Vs[(nt * 16 + lc) * 136 + w * 32 + mt * 16 + quad * 4] = pk;
        }
    }
    __syncthreads();
    // 64x128 shorts = 1024 uint4 -> 4 iterations of 256 threads
    #pragma unroll
    for (int i = 0; i < 4; i++) {
        int idx = i * 256 + t;                 // [0,1024)
        int d = idx >> 4, ch = (idx & 15) * 8;
        uint4 rd = *(const uint4*)&Vs[d * 136 + ch];
        *(uint4*)(vt + ((size_t)b * 64 + d) * 512 + l0 + ch) = rd;
    }
}

// ---------------------------------------------------------------------------
// Kernel B: MFMA flash attention + pooling. Block = (b, 128-row q-tile),
// 4 waves x 32 rows. K and V staged per 64-key stage in MFMA-frag order
// (all LDS frag reads lane-contiguous 16B). LDS 27.6 KB. No-max softmax.
// ---------------------------------------------------------------------------
__global__ __launch_bounds__(256) void attn_mfma(
    const unsigned short* __restrict__ q, const unsigned short* __restrict__ k,
    const unsigned short* __restrict__ vt, float* __restrict__ partial)
{
    const int b = blockIdx.x, qt = blockIdx.y, t = threadIdx.x;
    const int w = t >> 6, lane = t & 63, quad = lane >> 4, lc = lane & 15;

    __shared__ unsigned short Kb[4096];        // 64 keys x 64 d, frag order
    __shared__ unsigned short Vb[4096];        // 64 d x 64 keys, frag order
    __shared__ unsigned short Ps[4][2][16][40];
    __shared__ float red[4][64];

    bf16x8 aQ[2][2];
    #pragma unroll
    for (int rt = 0; rt < 2; rt++) {
        const unsigned short* qrow =
            q + (size_t)(b * LL + qt * 128 + w * 32 + rt * 16 + lc) * 64;
        aQ[rt][0] = *(const bf16x8*)(qrow + quad * 8);
        aQ[rt][1] = *(const bf16x8*)(qrow + 32 + quad * 8);
    }

    f32x4 outacc[2][4];
    #pragma unroll
    for (int rt = 0; rt < 2; rt++)
        #pragma unroll
        for (int dt = 0; dt < 4; dt++) outacc[rt][dt] = (f32x4){0.f, 0.f, 0.f, 0.f};
    float den[2][4] = {{0.f, 0.f, 0.f, 0.f}, {0.f, 0.f, 0.f, 0.f}};

    const unsigned short* kbase = k + (size_t)b * LL * 64;
    const unsigned short* vbase = vt + (size_t)b * 64 * 512;

    for (int s = 0; s < 8; s++) {              // 8 stages of 64 keys
        __syncthreads();
        #pragma unroll
        for (int uu = 0; uu < 2; uu++) {       // frag-order staging, 2 combos/wave
            int u = w * 2 + uu;
            {   int cc = u >> 2, nt = (u >> 1) & 1, kc = u & 1;
                uint4 rd = *(const uint4*)(kbase +
                    (size_t)(s * 64 + cc * 32 + nt * 16 + lc) * 64 + kc * 32 + quad * 8);
                *(uint4*)&Kb[u * 512 + lane * 8] = rd; }
            {   int cc = u >> 2, dt = u & 3;
                uint4 rd = *(const uint4*)(vbase +
                    (size_t)(dt * 16 + lc) * 512 + s * 64 + cc * 32 + quad * 8);
                *(uint4*)&Vb[u * 512 + lane * 8] = rd; }
        }
        __syncthreads();
        #pragma unroll
        for (int cc = 0; cc < 2; cc++) {       // 32 keys per chunk
            bf16x8 bK[2][2];
            #pragma unroll
            for (int nt = 0; nt < 2; nt++)
                #pragma unroll
                for (int kc = 0; kc < 2; kc++)
                    bK[nt][kc] = *(const bf16x8*)&Kb[(cc * 4 + nt * 2 + kc) * 512 + lane * 8];
            #pragma unroll
            for (int rt = 0; rt < 2; rt++)
                #pragma unroll
                for (int nt = 0; nt < 2; nt++) {
                    f32x4 sv = {0.f, 0.f, 0.f, 0.f};
                    sv = __builtin_amdgcn_mfma_f32_16x16x32_bf16(aQ[rt][0], bK[nt][0], sv, 0, 0, 0);
                    sv = __builtin_amdgcn_mfma_f32_16x16x32_bf16(aQ[rt][1], bK[nt][1], sv, 0, 0, 0);
                    #pragma unroll
                    for (int reg = 0; reg < 4; reg++) {
                        float p = __expf(sv[reg] * 0.125f);   // 1/sqrt(64)
                        den[rt][reg] += p;
                        Ps[w][rt][quad * 4 + reg][nt * 16 + lc] = f2b(p);
                    }
                }
            bf16x8 aP[2];                       // C->A via per-wave LDS (in-order)
            aP[0] = *(const bf16x8*)&Ps[w][0][lc][quad * 8];
            aP[1] = *(const bf16x8*)&Ps[w][1][lc][quad * 8];
            bf16x8 bV[4];
            #pragma unroll
            for (int dt = 0; dt < 4; dt++)
                bV[dt] = *(const bf16x8*)&Vb[(cc * 4 + dt) * 512 + lane * 8];
            #pragma unroll
            for (int rt = 0; rt < 2; rt++)
                #pragma unroll
                for (int dt = 0; dt < 4; dt++)
                    outacc[rt][dt] = __builtin_amdgcn_mfma_f32_16x16x32_bf16(
                        aP[rt], bV[dt], outacc[rt][dt], 0, 0, 0);
        }
    }

    // denominators: reduce over the quad's 16 lanes (key mod-16 classes)
    #pragma unroll
    for (int rt = 0; rt < 2; rt++)
        #pragma unroll
        for (int reg = 0; reg < 4; reg++) {
            float d2 = den[rt][reg];
            d2 += __shfl_xor(d2, 1);  d2 += __shfl_xor(d2, 2);
            d2 += __shfl_xor(d2, 4);  d2 += __shfl_xor(d2, 8);
            den[rt][reg] = d2;
        }
    // pooled partials over this wave's 32 rows
    #pragma unroll
    for (int dt = 0; dt < 4; dt++) {
        float ps = 0.f;
        #pragma unroll
        for (int rt = 0; rt < 2; rt++)
            #pragma unroll
            for (int reg = 0; reg < 4; reg++)
                ps += outacc[rt][dt][reg] / den[rt][reg];
        ps += __shfl_xor(ps, 16);
        ps += __shfl_xor(ps, 32);
        if (quad == 0) red[w][dt * 16 + lc] = ps;
    }
    __syncthreads();
    if (t < 64)
        partial[(size_t)(b * 4 + qt) * 64 + t] =
            red[0][t] + red[1][t] + red[2][t] + red[3][t];
}

// ---------------------------------------------------------------------------
// Kernel C: pooled = (sum of 4 partials)/512 ; logits = pooled @ fc_w^T + fc_b
// ---------------------------------------------------------------------------
__global__ __launch_bounds__(64) void fc_kernel(
    const float* __restrict__ partial,
    const float* __restrict__ fcw, const float* __restrict__ fcb,
    float* __restrict__ outp)
{
    const int b = blockIdx.x, t = threadIdx.x;
    __shared__ float pool[64];
    float s = 0.f;
    #pragma unroll
    for (int p = 0; p < 4; p++) s += partial[((size_t)b * 4 + p) * 64 + t];
    pool[t] = s * (1.0f / 512.0f);
    __syncthreads();
    if (t < NCLASS) {
        float acc = fcb[t];
        #pragma unroll
        for (int d = 0; d < 64; d++) acc += pool[d] * fcw[t * 64 + d];
        outp[b * NCLASS + t] = acc;
    }
}

// ---------------------------------------------------------------------------
extern "C" void kernel_launch(void* const* d_in, const int* in_sizes, int n_in,
                              void* d_out, int out_size, void* d_ws, size_t ws_size,
                              hipStream_t stream)
{
    const float* x   = (const float*)d_in[0];
    const float* w1  = (const float*)d_in[1];
    const float* cb1 = (const float*)d_in[2];
    const float* g1  = (const float*)d_in[3];
    const float* be1 = (const float*)d_in[4];
    const float* m1  = (const float*)d_in[5];
    const float* v1  = (const float*)d_in[6];
    const float* w2  = (const float*)d_in[7];
    const float* cb2 = (const float*)d_in[8];
    const float* g2  = (const float*)d_in[9];
    const float* be2 = (const float*)d_in[10];
    const float* m2  = (const float*)d_in[11];
    const float* v2  = (const float*)d_in[12];
    const float* wq  = (const float*)d_in[13];
    const float* bq  = (const float*)d_in[14];
    const float* wk  = (const float*)d_in[15];
    const float* bk  = (const float*)d_in[16];
    const float* wv  = (const float*)d_in[17];
    const float* bv  = (const float*)d_in[18];
    const float* fcw = (const float*)d_in[19];
    const float* fcb = (const float*)d_in[20];
    float* out = (float*)d_out;

    char* ws = (char*)d_ws;
    unsigned short* qo = (unsigned short*)(ws);                 // 16,777,216 B
    unsigned short* ko = (unsigned short*)(ws + 16777216u);
    unsigned short* vt = (unsigned short*)(ws + 33554432u);
    float* partial     = (float*)(ws + 50331648u);

    conv_qkv<<<dim3(NB, 4), 256, 0, stream>>>(x, w1, cb1, g1, be1, m1, v1,
                                              w2, cb2, g2, be2, m2, v2,
                                              wq, bq, wk, bk, wv, bv,
                                              qo, ko, vt);
    attn_mfma<<<dim3(NB, 4), 256, 0, stream>>>(qo, ko, vt, partial);
    fc_kernel<<<dim3(NB), 64, 0, stream>>>(partial, fcw, fcb, out);
}